// Round 8
// baseline (286.602 us; speedup 1.0000x reference)
//
#include <hip/hip_runtime.h>
#include <math.h>

// ---------------------------------------------------------------------------
// GIN, 3 layers, N=100000, E=1000000, D=64, fp32 in/out.
// Round 17: dual-tile interleaved gather. R16 post-mortem: each block is one
// short dependent chain (pbeg->csr->rows->FMA->MLP); residency ~2.75
// blocks/CU; VALU 47 / MFMA 7 / HBM 18 -> latency-bound. Fix: block = TWO
// independent 16-node tiles; gathers interleaved (A csr, B csr, A rows,
// B rows, A math, B math) -> 2x loads in flight per wave at the same serial
// depth; MLP per tile sequentially; 2x MFMA per barrier. Grid 3125 blocks.
//   - csr_pad stores src*128 (byte offset): no per-edge address multiply.
//   - min pad 16 (deg-0 nodes get 16 zero-weight entries) so the first
//     16-edge iteration is unconditional.
// Numerics identical (same per-node accumulation order, fmaf(0,..) pads).
// ---------------------------------------------------------------------------

#define FEAT  64
#define BINW  128          // nodes per bin
#define BSH   7            // log2(BINW)
#define NBLK  256          // edge-partition blocks
#define SRCB  25           // bits for src in packed key (N < 2^25)
#define PADSLACK 2048      // per-bin slack for padding (>= 128*16)

typedef __attribute__((ext_vector_type(8))) short bfrag;   // 8 bf16 (4 VGPRs)
typedef __attribute__((ext_vector_type(4))) float ffrag;   // 4 fp32 acc

__device__ __forceinline__ unsigned short f2bf_rne(float x) {
    union { float f; unsigned u; } v; v.f = x;
    unsigned r = (v.u + 0x7fffu + ((v.u >> 16) & 1u)) >> 16;
    return (unsigned short)r;
}
__device__ __forceinline__ float bf2f(unsigned short h) {
    union { unsigned u; float f; } v; v.u = ((unsigned)h) << 16;
    return v.f;
}

// ---------------- weight pack helper ---------------------------------------
__device__ __forceinline__ void pack_one(const float* __restrict__ w,
                                         unsigned short* __restrict__ hi,
                                         unsigned short* __restrict__ lo,
                                         int K, int Hc, int i) {
    int KF = K >> 5;
    int j    = i & 7;
    int lane = (i >> 3) & 63;
    int fb   = i >> 9;
    int kf   = fb % KF;
    int cg   = fb / KF;
    int k    = kf * 32 + ((lane >> 4) << 3) + j;
    int col  = cg * 16 + (lane & 15);
    float x = w[k * Hc + col];
    unsigned short h = f2bf_rne(x);
    hi[i] = h;
    lo[i] = f2bf_rne(x - bf2f(h));
}

// ---------------- pre: cvt + cnt + pack, one launch ------------------------
__global__ __launch_bounds__(256)
void k_pre(const float4* __restrict__ x4, ushort4* __restrict__ xb4,
           int n4, int gCvt,
           const int* __restrict__ dst, int* __restrict__ counts,
           int E, int NBINS,
           const float* w11, const float* w12, const float* w21,
           const float* w22, const float* w31, const float* w32,
           unsigned short* p11h, unsigned short* p11l,
           unsigned short* p12h, unsigned short* p12l,
           unsigned short* p21h, unsigned short* p21l,
           unsigned short* p22h, unsigned short* p22l,
           unsigned short* p31h, unsigned short* p31l,
           unsigned short* p32h, unsigned short* p32l) {
    __shared__ int h[1024];
    const int bb = blockIdx.x, tid = threadIdx.x;
    if (bb < gCvt) {
        int i = bb * 256 + tid;
        if (i < n4) {
            float4 v = x4[i];
            ushort4 o;
            o.x = f2bf_rne(v.x); o.y = f2bf_rne(v.y);
            o.z = f2bf_rne(v.z); o.w = f2bf_rne(v.w);
            xb4[i] = o;
        }
    } else if (bb < gCvt + NBLK) {
        const int b = bb - gCvt;
        for (int i = tid; i < NBINS; i += 256) h[i] = 0;
        __syncthreads();
        const int chunk = (E + NBLK - 1) / NBLK;
        const int ebeg = b * chunk;
        const int eend = (ebeg + chunk < E) ? ebeg + chunk : E;
        for (int e = ebeg + tid; e < eend; e += 256)
            atomicAdd(&h[dst[e] >> BSH], 1);          // LDS atomic
        __syncthreads();
        for (int i = tid; i < NBINS; i += 256)
            counts[i * NBLK + b] = h[i];
    } else {
        int i = (bb - gCvt - NBLK) * 256 + tid;       // 0..32767
        if      (i <  4096) pack_one(w11, p11h, p11l,  64,  64, i);
        else if (i <  8192) pack_one(w12, p12h, p12l,  64,  64, i - 4096);
        else if (i < 16384) pack_one(w21, p21h, p21l,  64, 128, i - 8192);
        else if (i < 24576) pack_one(w22, p22h, p22l, 128,  64, i - 16384);
        else if (i < 28672) pack_one(w31, p31h, p31l,  64,  64, i - 24576);
        else                pack_one(w32, p32h, p32l,  64,  64, i - 28672);
    }
}

// ---------------- per-bin scan over the 256 partition blocks ---------------
__global__ __launch_bounds__(256)
void k_scanA2(int* __restrict__ counts, int* __restrict__ bintotal, int NBINS) {
    __shared__ int tmp[256];
    const int bin = blockIdx.x, tid = threadIdx.x;
    int c = counts[bin * NBLK + tid];
    tmp[tid] = c;
    __syncthreads();
    for (int off = 1; off < 256; off <<= 1) {
        int t = (tid >= off) ? tmp[tid - off] : 0;
        __syncthreads();
        tmp[tid] += t;
        __syncthreads();
    }
    counts[bin * NBLK + tid] = tmp[tid] - c;      // exclusive within bin
    if (tid == 255) bintotal[bin] = tmp[255];
}

// ---------------- place edges (local binstart scan, no scanB) --------------
__global__ __launch_bounds__(256)
void k_place2(const int* __restrict__ src, const int* __restrict__ dst,
              const float* __restrict__ ew, const int* __restrict__ counts,
              const int* __restrict__ bintotal, int* __restrict__ binstart,
              int2* __restrict__ binbuf, int E, int NBINS) {
    __shared__ int bs[1024];        // local exclusive prefix of bintotal
    __shared__ int tmp[256];
    __shared__ int base[1024];
    const int b = blockIdx.x, tid = threadIdx.x;

    int v[4]; int s = 0;
#pragma unroll
    for (int j = 0; j < 4; ++j) {
        int idx = tid * 4 + j;
        v[j] = (idx < NBINS) ? bintotal[idx] : 0;
        s += v[j];
    }
    tmp[tid] = s;
    __syncthreads();
    for (int off = 1; off < 256; off <<= 1) {
        int t = (tid >= off) ? tmp[tid - off] : 0;
        __syncthreads();
        tmp[tid] += t;
        __syncthreads();
    }
    int run = tmp[tid] - s;
#pragma unroll
    for (int j = 0; j < 4; ++j) {
        bs[tid * 4 + j] = run;
        run += v[j];
    }
    __syncthreads();

    if (b == 0) {
        for (int i = tid; i < NBINS; i += 256) binstart[i] = bs[i];
        if (tid == 0) binstart[NBINS] = E;
    }

    for (int i = tid; i < NBINS; i += 256)
        base[i] = bs[i] + counts[i * NBLK + b];
    __syncthreads();

    const int chunk = (E + NBLK - 1) / NBLK;
    const int ebeg = b * chunk;
    const int eend = (ebeg + chunk < E) ? ebeg + chunk : E;
    for (int e = ebeg + tid; e < eend; e += 256) {
        int d = dst[e];
        int slot = atomicAdd(&base[d >> BSH], 1);   // LDS atomic only
        int key = ((d & (BINW - 1)) << SRCB) | src[e];
        binbuf[slot] = make_int2(key, __float_as_int(ew[e]));
    }
}

// one block per bin: count -> padded scan -> pbeg/pend -> place + pad fill.
// csr_pad.x stores src*128 (byte offset of the source row).
__global__ __launch_bounds__(256)
void k_binsort(const int2* __restrict__ binbuf, const int* __restrict__ binstart,
               int* __restrict__ pbeg, int* __restrict__ pend,
               int2* __restrict__ csr_pad, int N) {
    __shared__ int cnt[BINW];
    __shared__ int cur[BINW];
    __shared__ int pex[BINW];
    const int b    = blockIdx.x;
    const int base = binstart[b];
    const int ne   = binstart[b + 1] - base;
    const int tid  = threadIdx.x;
    const int base_pad = ((base + 15) & ~15) + b * PADSLACK;  // 16-aligned

    if (tid < BINW) cnt[tid] = 0;
    __syncthreads();
    for (int i = tid; i < ne; i += 256)
        atomicAdd(&cnt[(binbuf[base + i].x >> SRCB) & (BINW - 1)], 1);
    __syncthreads();
    int pc = 0;
    if (tid < BINW) {
        int c = cnt[tid];
        pc = c ? ((c + 15) & ~15) : 16;    // min pad 16
        cur[tid] = pc;
    }
    __syncthreads();
    for (int off = 1; off < BINW; off <<= 1) {
        int v = (tid < BINW && tid >= off) ? cur[tid - off] : 0;
        __syncthreads();
        if (tid < BINW) cur[tid] += v;
        __syncthreads();
    }
    if (tid < BINW) {
        int ex = cur[tid] - pc;            // exclusive padded prefix
        pex[tid] = ex;
        int node = b * BINW + tid;
        if (node < N) {
            pbeg[node] = base_pad + ex;
            pend[node] = base_pad + ex + pc;
        }
        cur[tid] = 0;                      // rank cursor
    }
    __syncthreads();
    for (int i = tid; i < ne; i += 256) {
        int2 e = binbuf[base + i];
        int dl = (e.x >> SRCB) & (BINW - 1);
        int r = atomicAdd(&cur[dl], 1);
        csr_pad[base_pad + pex[dl] + r] =
            make_int2((e.x & ((1 << SRCB) - 1)) << 7, e.y);
    }
    __syncthreads();
    if (tid < BINW) {                      // zero-weight padding entries
        int c = cnt[tid];
        int pcn = c ? ((c + 15) & ~15) : 16;
        int o = base_pad + pex[tid];
        for (int j = c; j < pcn; ++j)
            csr_pad[o + j] = make_int2(0, 0);
    }
}

// ---------------- fused gather + MLP (dual-tile, interleaved) --------------
// Block = 4 waves, TWO 16-node tiles (32 nodes). Wave wk's 16-lane group q
// gathers nodeA = blk*32+wk*4+q and nodeB = nodeA+16 with interleaved loads
// (2x in flight). MLP runs per tile sequentially; per tile: phase-1 cg split
// 4 ways, phase-2 one cg per wave.
template<int H, bool RELU_OUT, bool OUT_BF16>
__global__ __launch_bounds__(256)
void k_fused(const ushort* __restrict__ in, void* __restrict__ outv,
             const int* __restrict__ pbeg, const int* __restrict__ pend,
             const int2* __restrict__ csr_pad,
             const unsigned short* __restrict__ w1h, const unsigned short* __restrict__ w1l,
             const float* __restrict__ b1,
             const unsigned short* __restrict__ w2h, const unsigned short* __restrict__ w2l,
             const float* __restrict__ b2, int N) {
    constexpr int SH   = H + 4;      // LDS h-row stride
    constexpr int CG1  = H / 16;     // phase-1 col groups (split across 4 waves)
    constexpr int CGH1 = CG1 / 4;    // per-wave phase-1 col groups
    constexpr int KF2  = H / 32;     // phase-2 k frags
    __shared__ float hs[2 * 16 * SH];    // two 16-node tiles

    const int t = threadIdx.x;
    const int wk = t >> 6, lane = t & 63;     // wave 0..3
    const int m = lane & 15, q = lane >> 4;
    const int m8 = m * 8;
    float* hwA = hs;
    float* hwB = hs + 16 * SH;
    const char* inB = reinterpret_cast<const char*>(in);
    const int4* csr4 = reinterpret_cast<const int4*>(csr_pad);

    const int nodeA = blockIdx.x * 32 + wk * 4 + q;   // N%32==0: always valid
    const int nodeB = nodeA + 16;
    const int begA = pbeg[nodeA], endA = pend[nodeA];
    const int begB = pbeg[nodeB], endB = pend[nodeB];
    ushort4 xrA = *reinterpret_cast<const ushort4*>(inB + nodeA * 128 + m8);
    ushort4 xrB = *reinterpret_cast<const ushort4*>(inB + nodeB * 128 + m8);

    float4 accA = make_float4(0.f, 0.f, 0.f, 0.f);
    float4 accB = make_float4(0.f, 0.f, 0.f, 0.f);

    // ---- first 16 edges of each tile, interleaved (32 rows in flight) ----
    {
        int4 eA[8], eB[8];
#pragma unroll
        for (int u = 0; u < 8; ++u) eA[u] = csr4[(begA >> 1) + u];
#pragma unroll
        for (int u = 0; u < 8; ++u) eB[u] = csr4[(begB >> 1) + u];
        ushort4 vA[16], vB[16];
#pragma unroll
        for (int u = 0; u < 8; ++u) {
            vA[2*u]   = *reinterpret_cast<const ushort4*>(inB + (unsigned)eA[u].x + m8);
            vA[2*u+1] = *reinterpret_cast<const ushort4*>(inB + (unsigned)eA[u].z + m8);
        }
#pragma unroll
        for (int u = 0; u < 8; ++u) {
            vB[2*u]   = *reinterpret_cast<const ushort4*>(inB + (unsigned)eB[u].x + m8);
            vB[2*u+1] = *reinterpret_cast<const ushort4*>(inB + (unsigned)eB[u].z + m8);
        }
#pragma unroll
        for (int u = 0; u < 8; ++u) {
            float w0 = __int_as_float(eA[u].y);
            float w1 = __int_as_float(eA[u].w);
            accA.x = fmaf(w0, bf2f(vA[2*u].x), accA.x);
            accA.y = fmaf(w0, bf2f(vA[2*u].y), accA.y);
            accA.z = fmaf(w0, bf2f(vA[2*u].z), accA.z);
            accA.w = fmaf(w0, bf2f(vA[2*u].w), accA.w);
            accA.x = fmaf(w1, bf2f(vA[2*u+1].x), accA.x);
            accA.y = fmaf(w1, bf2f(vA[2*u+1].y), accA.y);
            accA.z = fmaf(w1, bf2f(vA[2*u+1].z), accA.z);
            accA.w = fmaf(w1, bf2f(vA[2*u+1].w), accA.w);
        }
#pragma unroll
        for (int u = 0; u < 8; ++u) {
            float w0 = __int_as_float(eB[u].y);
            float w1 = __int_as_float(eB[u].w);
            accB.x = fmaf(w0, bf2f(vB[2*u].x), accB.x);
            accB.y = fmaf(w0, bf2f(vB[2*u].y), accB.y);
            accB.z = fmaf(w0, bf2f(vB[2*u].z), accB.z);
            accB.w = fmaf(w0, bf2f(vB[2*u].w), accB.w);
            accB.x = fmaf(w1, bf2f(vB[2*u+1].x), accB.x);
            accB.y = fmaf(w1, bf2f(vB[2*u+1].y), accB.y);
            accB.z = fmaf(w1, bf2f(vB[2*u+1].z), accB.z);
            accB.w = fmaf(w1, bf2f(vB[2*u+1].w), accB.w);
        }
    }
    // ---- remainders (deg > 16, ~3% of nodes), masked loops ----
    for (int p = begA + 16; p < endA; p += 16) {
        int4 e2[8];
#pragma unroll
        for (int u = 0; u < 8; ++u) e2[u] = csr4[(p >> 1) + u];
        ushort4 v4[16];
#pragma unroll
        for (int u = 0; u < 8; ++u) {
            v4[2*u]   = *reinterpret_cast<const ushort4*>(inB + (unsigned)e2[u].x + m8);
            v4[2*u+1] = *reinterpret_cast<const ushort4*>(inB + (unsigned)e2[u].z + m8);
        }
#pragma unroll
        for (int u = 0; u < 8; ++u) {
            float w0 = __int_as_float(e2[u].y);
            float w1 = __int_as_float(e2[u].w);
            accA.x = fmaf(w0, bf2f(v4[2*u].x), accA.x);
            accA.y = fmaf(w0, bf2f(v4[2*u].y), accA.y);
            accA.z = fmaf(w0, bf2f(v4[2*u].z), accA.z);
            accA.w = fmaf(w0, bf2f(v4[2*u].w), accA.w);
            accA.x = fmaf(w1, bf2f(v4[2*u+1].x), accA.x);
            accA.y = fmaf(w1, bf2f(v4[2*u+1].y), accA.y);
            accA.z = fmaf(w1, bf2f(v4[2*u+1].z), accA.z);
            accA.w = fmaf(w1, bf2f(v4[2*u+1].w), accA.w);
        }
    }
    for (int p = begB + 16; p < endB; p += 16) {
        int4 e2[8];
#pragma unroll
        for (int u = 0; u < 8; ++u) e2[u] = csr4[(p >> 1) + u];
        ushort4 v4[16];
#pragma unroll
        for (int u = 0; u < 8; ++u) {
            v4[2*u]   = *reinterpret_cast<const ushort4*>(inB + (unsigned)e2[u].x + m8);
            v4[2*u+1] = *reinterpret_cast<const ushort4*>(inB + (unsigned)e2[u].z + m8);
        }
#pragma unroll
        for (int u = 0; u < 8; ++u) {
            float w0 = __int_as_float(e2[u].y);
            float w1 = __int_as_float(e2[u].w);
            accB.x = fmaf(w0, bf2f(v4[2*u].x), accB.x);
            accB.y = fmaf(w0, bf2f(v4[2*u].y), accB.y);
            accB.z = fmaf(w0, bf2f(v4[2*u].z), accB.z);
            accB.w = fmaf(w0, bf2f(v4[2*u].w), accB.w);
            accB.x = fmaf(w1, bf2f(v4[2*u+1].x), accB.x);
            accB.y = fmaf(w1, bf2f(v4[2*u+1].y), accB.y);
            accB.z = fmaf(w1, bf2f(v4[2*u+1].z), accB.z);
            accB.w = fmaf(w1, bf2f(v4[2*u+1].w), accB.w);
        }
    }
    accA.x += bf2f(xrA.x); accA.y += bf2f(xrA.y);
    accA.z += bf2f(xrA.z); accA.w += bf2f(xrA.w);
    accB.x += bf2f(xrB.x); accB.y += bf2f(xrB.y);
    accB.z += bf2f(xrB.z); accB.w += bf2f(xrB.w);
    {
        const int nl = wk * 4 + q;
        *reinterpret_cast<float4*>(&hwA[nl * SH + m * 4]) = accA;
        *reinterpret_cast<float4*>(&hwB[nl * SH + m * 4]) = accB;
    }
    __syncthreads();   // both tiles complete

    const bfrag* w1hp = reinterpret_cast<const bfrag*>(w1h);
    const bfrag* w1lp = reinterpret_cast<const bfrag*>(w1l);
    const bfrag* w2hp = reinterpret_cast<const bfrag*>(w2h);
    const bfrag* w2lp = reinterpret_cast<const bfrag*>(w2l);

    // ---- per-tile MLP ----
    auto run_mlp = [&](float* hw, int tnode0) {
        bfrag ah[2], al[2];
#pragma unroll
        for (int kf = 0; kf < 2; ++kf) {
            const float* base = &hw[m * SH + kf * 32 + q * 8];
            float4 u0 = *reinterpret_cast<const float4*>(base);
            float4 u1 = *reinterpret_cast<const float4*>(base + 4);
            float u[8] = {u0.x, u0.y, u0.z, u0.w, u1.x, u1.y, u1.z, u1.w};
#pragma unroll
            for (int j = 0; j < 8; ++j) {
                unsigned short hb = f2bf_rne(u[j]);
                ah[kf][j] = (short)hb;
                al[kf][j] = (short)f2bf_rne(u[j] - bf2f(hb));
            }
        }
        __syncthreads();   // all A-frags read before h overwrites the tile

        __builtin_amdgcn_s_setprio(1);
#pragma unroll
        for (int cgi = 0; cgi < CGH1; ++cgi) {
            const int cg = wk * CGH1 + cgi;
            ffrag c = {0.f, 0.f, 0.f, 0.f};
#pragma unroll
            for (int kf = 0; kf < 2; ++kf) {
                bfrag bh = w1hp[(cg * 2 + kf) * 64 + lane];
                bfrag bl = w1lp[(cg * 2 + kf) * 64 + lane];
                c = __builtin_amdgcn_mfma_f32_16x16x32_bf16(ah[kf], bh, c, 0, 0, 0);
                c = __builtin_amdgcn_mfma_f32_16x16x32_bf16(al[kf], bh, c, 0, 0, 0);
                c = __builtin_amdgcn_mfma_f32_16x16x32_bf16(ah[kf], bl, c, 0, 0, 0);
            }
            float bias = b1[cg * 16 + m];
#pragma unroll
            for (int r = 0; r < 4; ++r) {
                float hv = fmaxf(c[r] + bias, 0.f);
                hw[(q * 4 + r) * SH + cg * 16 + m] = hv;   // row=node, col=h-col
            }
        }
        __builtin_amdgcn_s_setprio(0);
        __syncthreads();   // h complete

        bfrag gh[KF2], gl[KF2];
#pragma unroll
        for (int kf = 0; kf < KF2; ++kf) {
            const float* base = &hw[m * SH + kf * 32 + q * 8];
            float4 u0 = *reinterpret_cast<const float4*>(base);
            float4 u1 = *reinterpret_cast<const float4*>(base + 4);
            float u[8] = {u0.x, u0.y, u0.z, u0.w, u1.x, u1.y, u1.z, u1.w};
#pragma unroll
            for (int j = 0; j < 8; ++j) {
                unsigned short hb = f2bf_rne(u[j]);
                gh[kf][j] = (short)hb;
                gl[kf][j] = (short)f2bf_rne(u[j] - bf2f(hb));
            }
        }

        {
            const int cg = wk;
            ffrag c = {0.f, 0.f, 0.f, 0.f};
            __builtin_amdgcn_s_setprio(1);
#pragma unroll
            for (int kf = 0; kf < KF2; ++kf) {
                bfrag bh = w2hp[(cg * KF2 + kf) * 64 + lane];
                bfrag bl = w2lp[(cg * KF2 + kf) * 64 + lane];
                c = __builtin_amdgcn_mfma_f32_16x16x32_bf16(gh[kf], bh, c, 0, 0, 0);
                c = __builtin_amdgcn_mfma_f32_16x16x32_bf16(gl[kf], bh, c, 0, 0, 0);
                c = __builtin_amdgcn_mfma_f32_16x16x32_bf16(gh[kf], bl, c, 0, 0, 0);
            }
            __builtin_amdgcn_s_setprio(0);
            float bias = b2[cg * 16 + m];
#pragma unroll
            for (int r = 0; r < 4; ++r) {
                int nd = tnode0 + q * 4 + r;
                if (nd < N) {
                    float v = c[r] + bias;
                    if (RELU_OUT) v = fmaxf(v, 0.f);
                    if (OUT_BF16)
                        ((unsigned short*)outv)[(size_t)nd * FEAT + cg * 16 + m] = f2bf_rne(v);
                    else
                        ((float*)outv)[(size_t)nd * FEAT + cg * 16 + m] = v;
                }
            }
        }
    };

    run_mlp(hwA, blockIdx.x * 32);
    run_mlp(hwB, blockIdx.x * 32 + 16);
}

// ---------------------------------------------------------------------------
extern "C" void kernel_launch(void* const* d_in, const int* in_sizes, int n_in,
                              void* d_out, int out_size, void* d_ws, size_t ws_size,
                              hipStream_t stream) {
    const float* x   = (const float*)d_in[0];
    const int*   ei  = (const int*)  d_in[1];
    const float* ew  = (const float*)d_in[2];
    const float* w11 = (const float*)d_in[3];
    const float* b11 = (const float*)d_in[4];
    const float* w12 = (const float*)d_in[5];
    const float* b12 = (const float*)d_in[6];
    const float* w21 = (const float*)d_in[7];
    const float* b21 = (const float*)d_in[8];
    const float* w22 = (const float*)d_in[9];
    const float* b22 = (const float*)d_in[10];
    const float* w31 = (const float*)d_in[11];
    const float* b31 = (const float*)d_in[12];
    const float* w32 = (const float*)d_in[13];
    const float* b32 = (const float*)d_in[14];

    const int N = in_sizes[0] / FEAT;   // 100000
    const int E = in_sizes[2];          // 1000000
    const int* srci = ei;
    const int* dsti = ei + E;
    const int NBINS = (N + BINW - 1) >> BSH;   // 782

    // ---- workspace layout ----
    unsigned short* xb0 = (unsigned short*)d_ws;             // [N*64] bf16
    unsigned short* xb1 = xb0 + (size_t)N * FEAT;            // [N*64] bf16
    int*   pbeg     = (int*)(xb1 + (size_t)N * FEAT);        // [N]
    int*   pend     = pbeg + N;                              // [N]
    int*   counts   = pend + N;                              // [NBINS*NBLK]
    int*   bintotal = counts + NBINS * NBLK;                 // [NBINS]
    int*   binstart = bintotal + NBINS;                      // [NBINS+1]
    size_t a16 = ((size_t)(binstart + NBINS + 1) + 15) & ~(size_t)15;
    int2*  binbuf   = (int2*)a16;                            // [E] (key, w)
    int2*  csr_pad  = (int2*)(binbuf + E);                   // [E + NBINS*PADSLACK + 1024]
    size_t pk = (size_t)(csr_pad + E + (size_t)NBINS * PADSLACK + 1024);
    unsigned short* p11h = (unsigned short*)pk;              // 4096 each for 64x64
    unsigned short* p11l = p11h + 4096;
    unsigned short* p12h = p11l + 4096;
    unsigned short* p12l = p12h + 4096;
    unsigned short* p21h = p12l + 4096;                      // 8192 for 64x128
    unsigned short* p21l = p21h + 8192;
    unsigned short* p22h = p21l + 8192;                      // 8192 for 128x64
    unsigned short* p22l = p22h + 8192;
    unsigned short* p31h = p22l + 8192;
    unsigned short* p31l = p31h + 4096;
    unsigned short* p32h = p31l + 4096;
    unsigned short* p32l = p32h + 4096;
    float* outF = (float*)d_out;                             // [N*64]

    const int n4   = N * 16;
    const int gCvt = (n4 + 255) / 256;
    const int gMlp = (N + 31) / 32;            // 3125 blocks, 2 tiles each
    const int gPre = gCvt + NBLK + 128;

    // ---- pre: cvt + histogram + weight pack (one launch) ----
    k_pre<<<gPre, 256, 0, stream>>>((const float4*)x, (ushort4*)xb0, n4, gCvt,
                                    dsti, counts, E, NBINS,
                                    w11, w12, w21, w22, w31, w32,
                                    p11h, p11l, p12h, p12l, p21h, p21l,
                                    p22h, p22l, p31h, p31l, p32h, p32l);
    // ---- CSR build (padded, byte-offset src) ----
    k_scanA2 <<<NBINS, 256, 0, stream>>>(counts, bintotal, NBINS);
    k_place2 <<<NBLK,  256, 0, stream>>>(srci, dsti, ew, counts, bintotal,
                                         binstart, binbuf, E, NBINS);
    k_binsort<<<NBINS, 256, 0, stream>>>(binbuf, binstart, pbeg, pend,
                                         csr_pad, N);

    // ---- fused layers (double-buffered activations) ----
    k_fused<64,  true,  true ><<<gMlp, 256, 0, stream>>>(xb0, xb1, pbeg, pend, csr_pad,
                                                         p11h, p11l, b11, p12h, p12l, b12, N);
    k_fused<128, true,  true ><<<gMlp, 256, 0, stream>>>(xb1, xb0, pbeg, pend, csr_pad,
                                                         p21h, p21l, b21, p22h, p22l, b22, N);
    k_fused<64,  false, false><<<gMlp, 256, 0, stream>>>(xb0, outF, pbeg, pend, csr_pad,
                                                         p31h, p31l, b31, p32h, p32l, b32, N);
}

// Round 9
// 257.847 us; speedup vs baseline: 1.1115x; 1.1115x over previous
//
#include <hip/hip_runtime.h>
#include <math.h>

// ---------------------------------------------------------------------------
// GIN, 3 layers, N=100000, E=1000000, D=64, fp32 in/out.
// Round 18: revert R17 dual-tile (regressed: grid halved, occupancy 35->26),
// back to R16 structure (one 16-node tile, 4 waves, 6250 blocks) + VALU cuts:
//   - gather math as packed fp32: bf16 pairs unpacked {d<<16, d&0xffff0000}
//     into float2, accumulated with __builtin_elementwise_fma -> v_pk_fma_f32
//     (2 FMA/instr). Per-feature accumulation order unchanged.
//   - MLP frag prep via v_cvt_pk_bf16_f32 (inline asm, RNE == f2bf_rne):
//     hi = cvt_pk, residual = pk sub of unpacked hi, lo = cvt_pk.
//     ~22 VALU per 8 elems vs ~72 for the bit-twiddled path.
//   - csr_pad stores src*128 (byte offset), min pad 16 (from R17, safe).
//   - dead nd<N checks dropped (N % 16 == 0).
// CSR build + pre kernel unchanged from R16/R17.
// ---------------------------------------------------------------------------

#define FEAT  64
#define BINW  128          // nodes per bin
#define BSH   7            // log2(BINW)
#define NBLK  256          // edge-partition blocks
#define SRCB  25           // bits for src in packed key (N < 2^25)
#define PADSLACK 2048      // per-bin slack for padding (>= 128*16)

typedef __attribute__((ext_vector_type(8))) short bfrag;   // 8 bf16 (4 VGPRs)
typedef __attribute__((ext_vector_type(4))) float ffrag;   // 4 fp32 acc
typedef __attribute__((ext_vector_type(2))) float f32x2;   // packed fp32 pair

__device__ __forceinline__ unsigned short f2bf_rne(float x) {
    union { float f; unsigned u; } v; v.f = x;
    unsigned r = (v.u + 0x7fffu + ((v.u >> 16) & 1u)) >> 16;
    return (unsigned short)r;
}
__device__ __forceinline__ float bf2f(unsigned short h) {
    union { unsigned u; float f; } v; v.u = ((unsigned)h) << 16;
    return v.f;
}
// two bf16 packed in a dword -> float2 {lo, hi}
__device__ __forceinline__ f32x2 bf2x2(unsigned d) {
    f32x2 r;
    r.x = __uint_as_float(d << 16);
    r.y = __uint_as_float(d & 0xffff0000u);
    return r;
}
// pack 2 f32 -> 2 bf16 (RNE), lo in [15:0], hi in [31:16]
__device__ __forceinline__ unsigned cvt_pk_bf16(float a, float b) {
    unsigned r;
    asm("v_cvt_pk_bf16_f32 %0, %1, %2" : "=v"(r) : "v"(a), "v"(b));
    return r;
}
// split 8 f32 into bf16 hi-frag + lo-frag (residual), RNE both
__device__ __forceinline__ void split8(const float u[8], bfrag& hi, bfrag& lo) {
    union { unsigned d[4]; bfrag b; } ch, cl;
#pragma unroll
    for (int i = 0; i < 4; ++i) {
        unsigned h = cvt_pk_bf16(u[2*i], u[2*i+1]);
        float f0 = __uint_as_float(h << 16);
        float f1 = __uint_as_float(h & 0xffff0000u);
        ch.d[i] = h;
        cl.d[i] = cvt_pk_bf16(u[2*i] - f0, u[2*i+1] - f1);
    }
    hi = ch.b; lo = cl.b;
}

// ---------------- weight pack helper ---------------------------------------
__device__ __forceinline__ void pack_one(const float* __restrict__ w,
                                         unsigned short* __restrict__ hi,
                                         unsigned short* __restrict__ lo,
                                         int K, int Hc, int i) {
    int KF = K >> 5;
    int j    = i & 7;
    int lane = (i >> 3) & 63;
    int fb   = i >> 9;
    int kf   = fb % KF;
    int cg   = fb / KF;
    int k    = kf * 32 + ((lane >> 4) << 3) + j;
    int col  = cg * 16 + (lane & 15);
    float x = w[k * Hc + col];
    unsigned short h = f2bf_rne(x);
    hi[i] = h;
    lo[i] = f2bf_rne(x - bf2f(h));
}

// ---------------- pre: cvt + cnt + pack, one launch ------------------------
__global__ __launch_bounds__(256)
void k_pre(const float4* __restrict__ x4, ushort4* __restrict__ xb4,
           int n4, int gCvt,
           const int* __restrict__ dst, int* __restrict__ counts,
           int E, int NBINS,
           const float* w11, const float* w12, const float* w21,
           const float* w22, const float* w31, const float* w32,
           unsigned short* p11h, unsigned short* p11l,
           unsigned short* p12h, unsigned short* p12l,
           unsigned short* p21h, unsigned short* p21l,
           unsigned short* p22h, unsigned short* p22l,
           unsigned short* p31h, unsigned short* p31l,
           unsigned short* p32h, unsigned short* p32l) {
    __shared__ int h[1024];
    const int bb = blockIdx.x, tid = threadIdx.x;
    if (bb < gCvt) {
        int i = bb * 256 + tid;
        if (i < n4) {
            float4 v = x4[i];
            ushort4 o;
            o.x = f2bf_rne(v.x); o.y = f2bf_rne(v.y);
            o.z = f2bf_rne(v.z); o.w = f2bf_rne(v.w);
            xb4[i] = o;
        }
    } else if (bb < gCvt + NBLK) {
        const int b = bb - gCvt;
        for (int i = tid; i < NBINS; i += 256) h[i] = 0;
        __syncthreads();
        const int chunk = (E + NBLK - 1) / NBLK;
        const int ebeg = b * chunk;
        const int eend = (ebeg + chunk < E) ? ebeg + chunk : E;
        for (int e = ebeg + tid; e < eend; e += 256)
            atomicAdd(&h[dst[e] >> BSH], 1);          // LDS atomic
        __syncthreads();
        for (int i = tid; i < NBINS; i += 256)
            counts[i * NBLK + b] = h[i];
    } else {
        int i = (bb - gCvt - NBLK) * 256 + tid;       // 0..32767
        if      (i <  4096) pack_one(w11, p11h, p11l,  64,  64, i);
        else if (i <  8192) pack_one(w12, p12h, p12l,  64,  64, i - 4096);
        else if (i < 16384) pack_one(w21, p21h, p21l,  64, 128, i - 8192);
        else if (i < 24576) pack_one(w22, p22h, p22l, 128,  64, i - 16384);
        else if (i < 28672) pack_one(w31, p31h, p31l,  64,  64, i - 24576);
        else                pack_one(w32, p32h, p32l,  64,  64, i - 28672);
    }
}

// ---------------- per-bin scan over the 256 partition blocks ---------------
__global__ __launch_bounds__(256)
void k_scanA2(int* __restrict__ counts, int* __restrict__ bintotal, int NBINS) {
    __shared__ int tmp[256];
    const int bin = blockIdx.x, tid = threadIdx.x;
    int c = counts[bin * NBLK + tid];
    tmp[tid] = c;
    __syncthreads();
    for (int off = 1; off < 256; off <<= 1) {
        int t = (tid >= off) ? tmp[tid - off] : 0;
        __syncthreads();
        tmp[tid] += t;
        __syncthreads();
    }
    counts[bin * NBLK + tid] = tmp[tid] - c;      // exclusive within bin
    if (tid == 255) bintotal[bin] = tmp[255];
}

// ---------------- place edges (local binstart scan, no scanB) --------------
__global__ __launch_bounds__(256)
void k_place2(const int* __restrict__ src, const int* __restrict__ dst,
              const float* __restrict__ ew, const int* __restrict__ counts,
              const int* __restrict__ bintotal, int* __restrict__ binstart,
              int2* __restrict__ binbuf, int E, int NBINS) {
    __shared__ int bs[1024];        // local exclusive prefix of bintotal
    __shared__ int tmp[256];
    __shared__ int base[1024];
    const int b = blockIdx.x, tid = threadIdx.x;

    int v[4]; int s = 0;
#pragma unroll
    for (int j = 0; j < 4; ++j) {
        int idx = tid * 4 + j;
        v[j] = (idx < NBINS) ? bintotal[idx] : 0;
        s += v[j];
    }
    tmp[tid] = s;
    __syncthreads();
    for (int off = 1; off < 256; off <<= 1) {
        int t = (tid >= off) ? tmp[tid - off] : 0;
        __syncthreads();
        tmp[tid] += t;
        __syncthreads();
    }
    int run = tmp[tid] - s;
#pragma unroll
    for (int j = 0; j < 4; ++j) {
        bs[tid * 4 + j] = run;
        run += v[j];
    }
    __syncthreads();

    if (b == 0) {
        for (int i = tid; i < NBINS; i += 256) binstart[i] = bs[i];
        if (tid == 0) binstart[NBINS] = E;
    }

    for (int i = tid; i < NBINS; i += 256)
        base[i] = bs[i] + counts[i * NBLK + b];
    __syncthreads();

    const int chunk = (E + NBLK - 1) / NBLK;
    const int ebeg = b * chunk;
    const int eend = (ebeg + chunk < E) ? ebeg + chunk : E;
    for (int e = ebeg + tid; e < eend; e += 256) {
        int d = dst[e];
        int slot = atomicAdd(&base[d >> BSH], 1);   // LDS atomic only
        int key = ((d & (BINW - 1)) << SRCB) | src[e];
        binbuf[slot] = make_int2(key, __float_as_int(ew[e]));
    }
}

// one block per bin: count -> padded scan -> pbeg/pend -> place + pad fill.
// csr_pad.x stores src*128 (byte offset of the source row).
__global__ __launch_bounds__(256)
void k_binsort(const int2* __restrict__ binbuf, const int* __restrict__ binstart,
               int* __restrict__ pbeg, int* __restrict__ pend,
               int2* __restrict__ csr_pad, int N) {
    __shared__ int cnt[BINW];
    __shared__ int cur[BINW];
    __shared__ int pex[BINW];
    const int b    = blockIdx.x;
    const int base = binstart[b];
    const int ne   = binstart[b + 1] - base;
    const int tid  = threadIdx.x;
    const int base_pad = ((base + 15) & ~15) + b * PADSLACK;  // 16-aligned

    if (tid < BINW) cnt[tid] = 0;
    __syncthreads();
    for (int i = tid; i < ne; i += 256)
        atomicAdd(&cnt[(binbuf[base + i].x >> SRCB) & (BINW - 1)], 1);
    __syncthreads();
    int pc = 0;
    if (tid < BINW) {
        int c = cnt[tid];
        pc = c ? ((c + 15) & ~15) : 16;    // min pad 16
        cur[tid] = pc;
    }
    __syncthreads();
    for (int off = 1; off < BINW; off <<= 1) {
        int v = (tid < BINW && tid >= off) ? cur[tid - off] : 0;
        __syncthreads();
        if (tid < BINW) cur[tid] += v;
        __syncthreads();
    }
    if (tid < BINW) {
        int ex = cur[tid] - pc;            // exclusive padded prefix
        pex[tid] = ex;
        int node = b * BINW + tid;
        if (node < N) {
            pbeg[node] = base_pad + ex;
            pend[node] = base_pad + ex + pc;
        }
        cur[tid] = 0;                      // rank cursor
    }
    __syncthreads();
    for (int i = tid; i < ne; i += 256) {
        int2 e = binbuf[base + i];
        int dl = (e.x >> SRCB) & (BINW - 1);
        int r = atomicAdd(&cur[dl], 1);
        csr_pad[base_pad + pex[dl] + r] =
            make_int2((e.x & ((1 << SRCB) - 1)) << 7, e.y);
    }
    __syncthreads();
    if (tid < BINW) {                      // zero-weight padding entries
        int c = cnt[tid];
        int pcn = c ? ((c + 15) & ~15) : 16;
        int o = base_pad + pex[tid];
        for (int j = c; j < pcn; ++j)
            csr_pad[o + j] = make_int2(0, 0);
    }
}

// ---------------- fused gather + MLP (4-wave tile, padded CSR) -------------
// Block = 4 waves = ONE 16-node tile. Wave wk gathers nodes tnode0+wk*4+q
// (one node per 16-lane group, 16 edges in flight via 8x int4 loads, no
// conditionals, packed fp32 math). MLP split 4 ways: phase-1 cg split,
// phase-2 one cg per wave. Frag prep via v_cvt_pk_bf16_f32.
template<int H, bool RELU_OUT, bool OUT_BF16>
__global__ __launch_bounds__(256)
void k_fused(const ushort* __restrict__ in, void* __restrict__ outv,
             const int* __restrict__ pbeg, const int* __restrict__ pend,
             const int2* __restrict__ csr_pad,
             const unsigned short* __restrict__ w1h, const unsigned short* __restrict__ w1l,
             const float* __restrict__ b1,
             const unsigned short* __restrict__ w2h, const unsigned short* __restrict__ w2l,
             const float* __restrict__ b2, int N) {
    constexpr int SH   = H + 4;      // LDS h-row stride
    constexpr int CG1  = H / 16;     // phase-1 col groups (split across 4 waves)
    constexpr int CGH1 = CG1 / 4;    // per-wave phase-1 col groups
    constexpr int KF2  = H / 32;     // phase-2 k frags
    __shared__ float hs[16 * SH];    // one 16-node tile

    const int t = threadIdx.x;
    const int wk = t >> 6, lane = t & 63;     // wave-in-tile 0..3
    const int m = lane & 15, q = lane >> 4;
    const int m8 = m * 8;
    const int tnode0 = blockIdx.x * 16;
    float* hw = hs;
    const char* inB = reinterpret_cast<const char*>(in);
    const int4* csr4 = reinterpret_cast<const int4*>(csr_pad);

    // N % 16 == 0: every node in every tile is valid.
    const int gnode = tnode0 + wk * 4 + q;
    const int beg = pbeg[gnode];              // broadcast within 16-lane group
    const int end = pend[gnode];
    uint2 xr = *reinterpret_cast<const uint2*>(inB + (size_t)gnode * 128 + m8);

    // ---- gather: 4 nodes in parallel per wave, 16 edges in flight/group ----
    {
        const int nl = wk * 4 + q;            // row within tile 0..15
        f32x2 acc01 = {0.f, 0.f};
        f32x2 acc23 = {0.f, 0.f};
        for (int p = beg; p < end; p += 16) {
            int4 e2[8];
#pragma unroll
            for (int u = 0; u < 8; ++u)
                e2[u] = csr4[(p >> 1) + u];   // 2 edges per 16B load
            uint2 v2[16];
#pragma unroll
            for (int u = 0; u < 8; ++u) {
                v2[2*u]   = *reinterpret_cast<const uint2*>(inB + (unsigned)e2[u].x + m8);
                v2[2*u+1] = *reinterpret_cast<const uint2*>(inB + (unsigned)e2[u].z + m8);
            }
#pragma unroll
            for (int u = 0; u < 8; ++u) {
                f32x2 w0 = {__int_as_float(e2[u].y), __int_as_float(e2[u].y)};
                f32x2 w1 = {__int_as_float(e2[u].w), __int_as_float(e2[u].w)};
                acc01 = __builtin_elementwise_fma(w0, bf2x2(v2[2*u].x),   acc01);
                acc23 = __builtin_elementwise_fma(w0, bf2x2(v2[2*u].y),   acc23);
                acc01 = __builtin_elementwise_fma(w1, bf2x2(v2[2*u+1].x), acc01);
                acc23 = __builtin_elementwise_fma(w1, bf2x2(v2[2*u+1].y), acc23);
            }
        }
        acc01 = acc01 + bf2x2(xr.x);
        acc23 = acc23 + bf2x2(xr.y);
        float4 accv = make_float4(acc01.x, acc01.y, acc23.x, acc23.y);
        *reinterpret_cast<float4*>(&hw[nl * SH + m * 4]) = accv;
    }
    __syncthreads();   // tile rows complete (all 4 waves)

    // ---- A frags (K=64 -> 2 kf) from shared tile, split hi/lo ----
    const bfrag* w1hp = reinterpret_cast<const bfrag*>(w1h);
    const bfrag* w1lp = reinterpret_cast<const bfrag*>(w1l);
    const bfrag* w2hp = reinterpret_cast<const bfrag*>(w2h);
    const bfrag* w2lp = reinterpret_cast<const bfrag*>(w2l);

    bfrag ah[2], al[2];
#pragma unroll
    for (int kf = 0; kf < 2; ++kf) {
        const float* base = &hw[m * SH + kf * 32 + q * 8];
        float4 u0 = *reinterpret_cast<const float4*>(base);
        float4 u1 = *reinterpret_cast<const float4*>(base + 4);
        float u[8] = {u0.x, u0.y, u0.z, u0.w, u1.x, u1.y, u1.z, u1.w};
        split8(u, ah[kf], al[kf]);
    }
    __syncthreads();   // all A-frags read before h overwrites the tile

    // ---- phase 1: h = relu(A@W1 + b1) -> LDS (cg split across 4 waves) ----
    __builtin_amdgcn_s_setprio(1);
#pragma unroll
    for (int cgi = 0; cgi < CGH1; ++cgi) {
        const int cg = wk * CGH1 + cgi;
        ffrag c = {0.f, 0.f, 0.f, 0.f};
#pragma unroll
        for (int kf = 0; kf < 2; ++kf) {
            bfrag bh = w1hp[(cg * 2 + kf) * 64 + lane];
            bfrag bl = w1lp[(cg * 2 + kf) * 64 + lane];
            c = __builtin_amdgcn_mfma_f32_16x16x32_bf16(ah[kf], bh, c, 0, 0, 0);
            c = __builtin_amdgcn_mfma_f32_16x16x32_bf16(al[kf], bh, c, 0, 0, 0);
            c = __builtin_amdgcn_mfma_f32_16x16x32_bf16(ah[kf], bl, c, 0, 0, 0);
        }
        float bias = b1[cg * 16 + m];
#pragma unroll
        for (int r = 0; r < 4; ++r) {
            float hv = fmaxf(c[r] + bias, 0.f);
            hw[(q * 4 + r) * SH + cg * 16 + m] = hv;   // row=node, col=h-col
        }
    }
    __builtin_amdgcn_s_setprio(0);
    __syncthreads();   // h complete (all 4 waves)

    // ---- h -> A frags (hi/lo), full K per wave ----
    bfrag gh[KF2], gl[KF2];
#pragma unroll
    for (int kf = 0; kf < KF2; ++kf) {
        const float* base = &hw[m * SH + kf * 32 + q * 8];
        float4 u0 = *reinterpret_cast<const float4*>(base);
        float4 u1 = *reinterpret_cast<const float4*>(base + 4);
        float u[8] = {u0.x, u0.y, u0.z, u0.w, u1.x, u1.y, u1.z, u1.w};
        split8(u, gh[kf], gl[kf]);
    }

    // ---- phase 2: out = h@W2 + b2 (one output cg per wave) ----
    {
        const int cg = wk;
        ffrag c = {0.f, 0.f, 0.f, 0.f};
        __builtin_amdgcn_s_setprio(1);
#pragma unroll
        for (int kf = 0; kf < KF2; ++kf) {
            bfrag bh = w2hp[(cg * KF2 + kf) * 64 + lane];
            bfrag bl = w2lp[(cg * KF2 + kf) * 64 + lane];
            c = __builtin_amdgcn_mfma_f32_16x16x32_bf16(gh[kf], bh, c, 0, 0, 0);
            c = __builtin_amdgcn_mfma_f32_16x16x32_bf16(gl[kf], bh, c, 0, 0, 0);
            c = __builtin_amdgcn_mfma_f32_16x16x32_bf16(gh[kf], bl, c, 0, 0, 0);
        }
        __builtin_amdgcn_s_setprio(0);
        float bias = b2[cg * 16 + m];
#pragma unroll
        for (int r = 0; r < 4; ++r) {
            int nd = tnode0 + q * 4 + r;
            float v = c[r] + bias;
            if (RELU_OUT) v = fmaxf(v, 0.f);
            if (OUT_BF16)
                ((unsigned short*)outv)[(size_t)nd * FEAT + cg * 16 + m] = f2bf_rne(v);
            else
                ((float*)outv)[(size_t)nd * FEAT + cg * 16 + m] = v;
        }
    }
}

// ---------------------------------------------------------------------------
extern "C" void kernel_launch(void* const* d_in, const int* in_sizes, int n_in,
                              void* d_out, int out_size, void* d_ws, size_t ws_size,
                              hipStream_t stream) {
    const float* x   = (const float*)d_in[0];
    const int*   ei  = (const int*)  d_in[1];
    const float* ew  = (const float*)d_in[2];
    const float* w11 = (const float*)d_in[3];
    const float* b11 = (const float*)d_in[4];
    const float* w12 = (const float*)d_in[5];
    const float* b12 = (const float*)d_in[6];
    const float* w21 = (const float*)d_in[7];
    const float* b21 = (const float*)d_in[8];
    const float* w22 = (const float*)d_in[9];
    const float* b22 = (const float*)d_in[10];
    const float* w31 = (const float*)d_in[11];
    const float* b31 = (const float*)d_in[12];
    const float* w32 = (const float*)d_in[13];
    const float* b32 = (const float*)d_in[14];

    const int N = in_sizes[0] / FEAT;   // 100000
    const int E = in_sizes[2];          // 1000000
    const int* srci = ei;
    const int* dsti = ei + E;
    const int NBINS = (N + BINW - 1) >> BSH;   // 782

    // ---- workspace layout ----
    unsigned short* xb0 = (unsigned short*)d_ws;             // [N*64] bf16
    unsigned short* xb1 = xb0 + (size_t)N * FEAT;            // [N*64] bf16
    int*   pbeg     = (int*)(xb1 + (size_t)N * FEAT);        // [N]
    int*   pend     = pbeg + N;                              // [N]
    int*   counts   = pend + N;                              // [NBINS*NBLK]
    int*   bintotal = counts + NBINS * NBLK;                 // [NBINS]
    int*   binstart = bintotal + NBINS;                      // [NBINS+1]
    size_t a16 = ((size_t)(binstart + NBINS + 1) + 15) & ~(size_t)15;
    int2*  binbuf   = (int2*)a16;                            // [E] (key, w)
    int2*  csr_pad  = (int2*)(binbuf + E);                   // [E + NBINS*PADSLACK + 1024]
    size_t pk = (size_t)(csr_pad + E + (size_t)NBINS * PADSLACK + 1024);
    unsigned short* p11h = (unsigned short*)pk;              // 4096 each for 64x64
    unsigned short* p11l = p11h + 4096;
    unsigned short* p12h = p11l + 4096;
    unsigned short* p12l = p12h + 4096;
    unsigned short* p21h = p12l + 4096;                      // 8192 for 64x128
    unsigned short* p21l = p21h + 8192;
    unsigned short* p22h = p21l + 8192;                      // 8192 for 128x64
    unsigned short* p22l = p22h + 8192;
    unsigned short* p31h = p22l + 8192;
    unsigned short* p31l = p31h + 4096;
    unsigned short* p32h = p31l + 4096;
    unsigned short* p32l = p32h + 4096;
    float* outF = (float*)d_out;                             // [N*64]

    const int n4   = N * 16;
    const int gCvt = (n4 + 255) / 256;
    const int gMlp = (N + 15) / 16;            // 6250 blocks, 25000 waves
    const int gPre = gCvt + NBLK + 128;

    // ---- pre: cvt + histogram + weight pack (one launch) ----
    k_pre<<<gPre, 256, 0, stream>>>((const float4*)x, (ushort4*)xb0, n4, gCvt,
                                    dsti, counts, E, NBINS,
                                    w11, w12, w21, w22, w31, w32,
                                    p11h, p11l, p12h, p12l, p21h, p21l,
                                    p22h, p22l, p31h, p31l, p32h, p32l);
    // ---- CSR build (padded, byte-offset src) ----
    k_scanA2 <<<NBINS, 256, 0, stream>>>(counts, bintotal, NBINS);
    k_place2 <<<NBLK,  256, 0, stream>>>(srci, dsti, ew, counts, bintotal,
                                         binstart, binbuf, E, NBINS);
    k_binsort<<<NBINS, 256, 0, stream>>>(binbuf, binstart, pbeg, pend,
                                         csr_pad, N);

    // ---- fused layers (double-buffered activations) ----
    k_fused<64,  true,  true ><<<gMlp, 256, 0, stream>>>(xb0, xb1, pbeg, pend, csr_pad,
                                                         p11h, p11l, b11, p12h, p12l, b12, N);
    k_fused<128, true,  true ><<<gMlp, 256, 0, stream>>>(xb1, xb0, pbeg, pend, csr_pad,
                                                         p21h, p21l, b21, p22h, p22l, b22, N);
    k_fused<64,  false, false><<<gMlp, 256, 0, stream>>>(xb0, outF, pbeg, pend, csr_pad,
                                                         p31h, p31l, b31, p32h, p32l, b32, N);
}

// Round 10
// 252.827 us; speedup vs baseline: 1.1336x; 1.0199x over previous
//
#include <hip/hip_runtime.h>
#include <math.h>

// ---------------------------------------------------------------------------
// GIN, 3 layers, N=100000, E=1000000, D=64, fp32 in/out.
// Round 19: cut one memory-latency stage from the gather chain.
//   R18 post-mortem: chain was pbeg/pend -> csr meta -> rows -> math (2 full
//   round trips before math). Fix: first16[node][16] fixed-stride edge array
//   (meta address = f(node), no pointer load); deg>16 overflow via
//   hdr[node]=(obeg,ocnt) + ovfbuf, masked rare loop. 97% of nodes complete
//   in ONE round trip. Also: separate LDS h-buffer from the acc tile ->
//   barrier count 3 -> 2. Packed fp32 gather math + cvt_pk frag prep kept
//   from R18. Numerics unchanged (same per-node accumulation order,
//   fmaf(0,..) pads; within-node edge order from binsort cursors as before).
// ---------------------------------------------------------------------------

#define FEAT  64
#define BINW  128          // nodes per bin
#define BSH   7            // log2(BINW)
#define NBLK  256          // edge-partition blocks
#define SRCB  25           // bits for src in packed key (N < 2^25)
#define OVFSLACK 2048      // per-bin overflow slack (int2 entries)

typedef __attribute__((ext_vector_type(8))) short bfrag;   // 8 bf16 (4 VGPRs)
typedef __attribute__((ext_vector_type(4))) float ffrag;   // 4 fp32 acc
typedef __attribute__((ext_vector_type(2))) float f32x2;   // packed fp32 pair

__device__ __forceinline__ unsigned short f2bf_rne(float x) {
    union { float f; unsigned u; } v; v.f = x;
    unsigned r = (v.u + 0x7fffu + ((v.u >> 16) & 1u)) >> 16;
    return (unsigned short)r;
}
__device__ __forceinline__ float bf2f(unsigned short h) {
    union { unsigned u; float f; } v; v.u = ((unsigned)h) << 16;
    return v.f;
}
// two bf16 packed in a dword -> float2 {lo, hi}
__device__ __forceinline__ f32x2 bf2x2(unsigned d) {
    f32x2 r;
    r.x = __uint_as_float(d << 16);
    r.y = __uint_as_float(d & 0xffff0000u);
    return r;
}
// pack 2 f32 -> 2 bf16 (RNE), lo in [15:0], hi in [31:16]
__device__ __forceinline__ unsigned cvt_pk_bf16(float a, float b) {
    unsigned r;
    asm("v_cvt_pk_bf16_f32 %0, %1, %2" : "=v"(r) : "v"(a), "v"(b));
    return r;
}
// split 8 f32 into bf16 hi-frag + lo-frag (residual), RNE both
__device__ __forceinline__ void split8(const float u[8], bfrag& hi, bfrag& lo) {
    union { unsigned d[4]; bfrag b; } ch, cl;
#pragma unroll
    for (int i = 0; i < 4; ++i) {
        unsigned h = cvt_pk_bf16(u[2*i], u[2*i+1]);
        float f0 = __uint_as_float(h << 16);
        float f1 = __uint_as_float(h & 0xffff0000u);
        ch.d[i] = h;
        cl.d[i] = cvt_pk_bf16(u[2*i] - f0, u[2*i+1] - f1);
    }
    hi = ch.b; lo = cl.b;
}

// ---------------- weight pack helper ---------------------------------------
__device__ __forceinline__ void pack_one(const float* __restrict__ w,
                                         unsigned short* __restrict__ hi,
                                         unsigned short* __restrict__ lo,
                                         int K, int Hc, int i) {
    int KF = K >> 5;
    int j    = i & 7;
    int lane = (i >> 3) & 63;
    int fb   = i >> 9;
    int kf   = fb % KF;
    int cg   = fb / KF;
    int k    = kf * 32 + ((lane >> 4) << 3) + j;
    int col  = cg * 16 + (lane & 15);
    float x = w[k * Hc + col];
    unsigned short h = f2bf_rne(x);
    hi[i] = h;
    lo[i] = f2bf_rne(x - bf2f(h));
}

// ---------------- pre: cvt + cnt + pack, one launch ------------------------
__global__ __launch_bounds__(256)
void k_pre(const float4* __restrict__ x4, ushort4* __restrict__ xb4,
           int n4, int gCvt,
           const int* __restrict__ dst, int* __restrict__ counts,
           int E, int NBINS,
           const float* w11, const float* w12, const float* w21,
           const float* w22, const float* w31, const float* w32,
           unsigned short* p11h, unsigned short* p11l,
           unsigned short* p12h, unsigned short* p12l,
           unsigned short* p21h, unsigned short* p21l,
           unsigned short* p22h, unsigned short* p22l,
           unsigned short* p31h, unsigned short* p31l,
           unsigned short* p32h, unsigned short* p32l) {
    __shared__ int h[1024];
    const int bb = blockIdx.x, tid = threadIdx.x;
    if (bb < gCvt) {
        int i = bb * 256 + tid;
        if (i < n4) {
            float4 v = x4[i];
            ushort4 o;
            o.x = f2bf_rne(v.x); o.y = f2bf_rne(v.y);
            o.z = f2bf_rne(v.z); o.w = f2bf_rne(v.w);
            xb4[i] = o;
        }
    } else if (bb < gCvt + NBLK) {
        const int b = bb - gCvt;
        for (int i = tid; i < NBINS; i += 256) h[i] = 0;
        __syncthreads();
        const int chunk = (E + NBLK - 1) / NBLK;
        const int ebeg = b * chunk;
        const int eend = (ebeg + chunk < E) ? ebeg + chunk : E;
        for (int e = ebeg + tid; e < eend; e += 256)
            atomicAdd(&h[dst[e] >> BSH], 1);          // LDS atomic
        __syncthreads();
        for (int i = tid; i < NBINS; i += 256)
            counts[i * NBLK + b] = h[i];
    } else {
        int i = (bb - gCvt - NBLK) * 256 + tid;       // 0..32767
        if      (i <  4096) pack_one(w11, p11h, p11l,  64,  64, i);
        else if (i <  8192) pack_one(w12, p12h, p12l,  64,  64, i - 4096);
        else if (i < 16384) pack_one(w21, p21h, p21l,  64, 128, i - 8192);
        else if (i < 24576) pack_one(w22, p22h, p22l, 128,  64, i - 16384);
        else if (i < 28672) pack_one(w31, p31h, p31l,  64,  64, i - 24576);
        else                pack_one(w32, p32h, p32l,  64,  64, i - 28672);
    }
}

// ---------------- per-bin scan over the 256 partition blocks ---------------
__global__ __launch_bounds__(256)
void k_scanA2(int* __restrict__ counts, int* __restrict__ bintotal, int NBINS) {
    __shared__ int tmp[256];
    const int bin = blockIdx.x, tid = threadIdx.x;
    int c = counts[bin * NBLK + tid];
    tmp[tid] = c;
    __syncthreads();
    for (int off = 1; off < 256; off <<= 1) {
        int t = (tid >= off) ? tmp[tid - off] : 0;
        __syncthreads();
        tmp[tid] += t;
        __syncthreads();
    }
    counts[bin * NBLK + tid] = tmp[tid] - c;      // exclusive within bin
    if (tid == 255) bintotal[bin] = tmp[255];
}

// ---------------- place edges (local binstart scan) ------------------------
__global__ __launch_bounds__(256)
void k_place2(const int* __restrict__ src, const int* __restrict__ dst,
              const float* __restrict__ ew, const int* __restrict__ counts,
              const int* __restrict__ bintotal, int* __restrict__ binstart,
              int2* __restrict__ binbuf, int E, int NBINS) {
    __shared__ int bs[1024];        // local exclusive prefix of bintotal
    __shared__ int tmp[256];
    __shared__ int base[1024];
    const int b = blockIdx.x, tid = threadIdx.x;

    int v[4]; int s = 0;
#pragma unroll
    for (int j = 0; j < 4; ++j) {
        int idx = tid * 4 + j;
        v[j] = (idx < NBINS) ? bintotal[idx] : 0;
        s += v[j];
    }
    tmp[tid] = s;
    __syncthreads();
    for (int off = 1; off < 256; off <<= 1) {
        int t = (tid >= off) ? tmp[tid - off] : 0;
        __syncthreads();
        tmp[tid] += t;
        __syncthreads();
    }
    int run = tmp[tid] - s;
#pragma unroll
    for (int j = 0; j < 4; ++j) {
        bs[tid * 4 + j] = run;
        run += v[j];
    }
    __syncthreads();

    if (b == 0) {
        for (int i = tid; i < NBINS; i += 256) binstart[i] = bs[i];
        if (tid == 0) binstart[NBINS] = E;
    }

    for (int i = tid; i < NBINS; i += 256)
        base[i] = bs[i] + counts[i * NBLK + b];
    __syncthreads();

    const int chunk = (E + NBLK - 1) / NBLK;
    const int ebeg = b * chunk;
    const int eend = (ebeg + chunk < E) ? ebeg + chunk : E;
    for (int e = ebeg + tid; e < eend; e += 256) {
        int d = dst[e];
        int slot = atomicAdd(&base[d >> BSH], 1);   // LDS atomic only
        int key = ((d & (BINW - 1)) << SRCB) | src[e];
        binbuf[slot] = make_int2(key, __float_as_int(ew[e]));
    }
}

// one block per bin: count -> first16/overflow split -> hdr + fills.
// first16[node][r] (r<16) and ovfbuf entries store (src*128, w).
__global__ __launch_bounds__(256)
void k_binsort(const int2* __restrict__ binbuf, const int* __restrict__ binstart,
               int2* __restrict__ hdr, int2* __restrict__ first16,
               int2* __restrict__ ovfbuf, int N) {
    __shared__ int cnt[BINW];
    __shared__ int cur[BINW];
    __shared__ int oex[BINW];
    const int b    = blockIdx.x;
    const int base = binstart[b];
    const int ne   = binstart[b + 1] - base;
    const int tid  = threadIdx.x;
    const int obase = b * OVFSLACK;        // int2 index into ovfbuf (even)

    if (tid < BINW) cnt[tid] = 0;
    __syncthreads();
    for (int i = tid; i < ne; i += 256)
        atomicAdd(&cnt[(binbuf[base + i].x >> SRCB) & (BINW - 1)], 1);
    __syncthreads();
    int opc = 0;
    if (tid < BINW) {
        int c = cnt[tid];
        opc = (c > 16) ? ((c - 16 + 15) & ~15) : 0;   // padded overflow count
        cur[tid] = opc;
    }
    __syncthreads();
    for (int off = 1; off < BINW; off <<= 1) {
        int v = (tid < BINW && tid >= off) ? cur[tid - off] : 0;
        __syncthreads();
        if (tid < BINW) cur[tid] += v;
        __syncthreads();
    }
    if (tid < BINW) {
        int ex = cur[tid] - opc;           // exclusive padded overflow prefix
        oex[tid] = ex;
        int node = b * BINW + tid;
        if (node < N) hdr[node] = make_int2(obase + ex, opc);
        cur[tid] = 0;                      // rank cursor
    }
    __syncthreads();
    for (int i = tid; i < ne; i += 256) {
        int2 e = binbuf[base + i];
        int dl = (e.x >> SRCB) & (BINW - 1);
        int r = atomicAdd(&cur[dl], 1);
        int2 out = make_int2((e.x & ((1 << SRCB) - 1)) << 7, e.y);
        int node = b * BINW + dl;
        if (r < 16) first16[(size_t)node * 16 + r] = out;
        else        ovfbuf[obase + oex[dl] + (r - 16)] = out;
    }
    __syncthreads();
    if (tid < BINW) {                      // zero-weight padding
        int c = cnt[tid];
        int node = b * BINW + tid;
        if (node < N) {
            for (int j = c; j < 16; ++j)
                first16[(size_t)node * 16 + j] = make_int2(0, 0);
            int opcn = (c > 16) ? ((c - 16 + 15) & ~15) : 0;
            if (opcn > 0) {
                int o = obase + oex[tid];
                for (int j = c - 16; j < opcn; ++j)
                    ovfbuf[o + j] = make_int2(0, 0);
            }
        }
    }
}

// ---------------- fused gather + MLP (4-wave tile, first16 CSR) ------------
// Block = 4 waves = ONE 16-node tile. Group (wk,q) gathers node
// tnode0+wk*4+q: first16 meta address = f(node) (no pointer chase), 16 rows
// in one round trip; rare deg>16 overflow via hdr+ovfbuf masked loop.
// MLP: acc tile and h in SEPARATE LDS buffers -> only 2 barriers.
template<int H, bool RELU_OUT, bool OUT_BF16>
__global__ __launch_bounds__(256)
void k_fused(const ushort* __restrict__ in, void* __restrict__ outv,
             const int2* __restrict__ hdr, const int2* __restrict__ first16,
             const int2* __restrict__ ovfbuf,
             const unsigned short* __restrict__ w1h, const unsigned short* __restrict__ w1l,
             const float* __restrict__ b1,
             const unsigned short* __restrict__ w2h, const unsigned short* __restrict__ w2l,
             const float* __restrict__ b2, int N) {
    constexpr int SA   = 68;         // acc tile stride (64 + 4)
    constexpr int SH1  = H + 4;      // h tile stride
    constexpr int CG1  = H / 16;     // phase-1 col groups (split across 4 waves)
    constexpr int CGH1 = CG1 / 4;    // per-wave phase-1 col groups
    constexpr int KF2  = H / 32;     // phase-2 k frags
    __shared__ float hs_acc[16 * SA];
    __shared__ float hs_h[16 * SH1];

    const int t = threadIdx.x;
    const int wk = t >> 6, lane = t & 63;     // wave-in-tile 0..3
    const int m = lane & 15, q = lane >> 4;
    const int m8 = m * 8;
    const int tnode0 = blockIdx.x * 16;
    const char* inB = reinterpret_cast<const char*>(in);

    // N % 16 == 0: every node in every tile is valid.
    const int gnode = tnode0 + wk * 4 + q;
    const int2 hd = hdr[gnode];               // overflow meta (rarely used)
    uint2 xr = *reinterpret_cast<const uint2*>(inB + (size_t)gnode * 128 + m8);
    const int4* f16 = reinterpret_cast<const int4*>(first16) + (size_t)gnode * 8;

    f32x2 acc01 = {0.f, 0.f};
    f32x2 acc23 = {0.f, 0.f};

    // ---- first 16 edges: meta address known immediately, one round trip ----
    {
        int4 e2[8];
#pragma unroll
        for (int u = 0; u < 8; ++u)
            e2[u] = f16[u];                   // contiguous 128B per node
        uint2 v2[16];
#pragma unroll
        for (int u = 0; u < 8; ++u) {
            v2[2*u]   = *reinterpret_cast<const uint2*>(inB + (unsigned)e2[u].x + m8);
            v2[2*u+1] = *reinterpret_cast<const uint2*>(inB + (unsigned)e2[u].z + m8);
        }
#pragma unroll
        for (int u = 0; u < 8; ++u) {
            f32x2 w0 = {__int_as_float(e2[u].y), __int_as_float(e2[u].y)};
            f32x2 w1 = {__int_as_float(e2[u].w), __int_as_float(e2[u].w)};
            acc01 = __builtin_elementwise_fma(w0, bf2x2(v2[2*u].x),   acc01);
            acc23 = __builtin_elementwise_fma(w0, bf2x2(v2[2*u].y),   acc23);
            acc01 = __builtin_elementwise_fma(w1, bf2x2(v2[2*u+1].x), acc01);
            acc23 = __builtin_elementwise_fma(w1, bf2x2(v2[2*u+1].y), acc23);
        }
    }
    // ---- overflow (deg > 16, ~3% of nodes), masked rare loop ----
    if (hd.y > 0) {
        const int4* ovf4 = reinterpret_cast<const int4*>(ovfbuf);
        for (int p = hd.x; p < hd.x + hd.y; p += 16) {
            int4 e2[8];
#pragma unroll
            for (int u = 0; u < 8; ++u)
                e2[u] = ovf4[(p >> 1) + u];
            uint2 v2[16];
#pragma unroll
            for (int u = 0; u < 8; ++u) {
                v2[2*u]   = *reinterpret_cast<const uint2*>(inB + (unsigned)e2[u].x + m8);
                v2[2*u+1] = *reinterpret_cast<const uint2*>(inB + (unsigned)e2[u].z + m8);
            }
#pragma unroll
            for (int u = 0; u < 8; ++u) {
                f32x2 w0 = {__int_as_float(e2[u].y), __int_as_float(e2[u].y)};
                f32x2 w1 = {__int_as_float(e2[u].w), __int_as_float(e2[u].w)};
                acc01 = __builtin_elementwise_fma(w0, bf2x2(v2[2*u].x),   acc01);
                acc23 = __builtin_elementwise_fma(w0, bf2x2(v2[2*u].y),   acc23);
                acc01 = __builtin_elementwise_fma(w1, bf2x2(v2[2*u+1].x), acc01);
                acc23 = __builtin_elementwise_fma(w1, bf2x2(v2[2*u+1].y), acc23);
            }
        }
    }
    acc01 = acc01 + bf2x2(xr.x);
    acc23 = acc23 + bf2x2(xr.y);
    {
        const int nl = wk * 4 + q;            // row within tile 0..15
        float4 accv = make_float4(acc01.x, acc01.y, acc23.x, acc23.y);
        *reinterpret_cast<float4*>(&hs_acc[nl * SA + m * 4]) = accv;
    }
    __syncthreads();   // barrier 1: tile rows complete

    // ---- A frags (K=64 -> 2 kf) from acc tile, split hi/lo ----
    const bfrag* w1hp = reinterpret_cast<const bfrag*>(w1h);
    const bfrag* w1lp = reinterpret_cast<const bfrag*>(w1l);
    const bfrag* w2hp = reinterpret_cast<const bfrag*>(w2h);
    const bfrag* w2lp = reinterpret_cast<const bfrag*>(w2l);

    bfrag ah[2], al[2];
#pragma unroll
    for (int kf = 0; kf < 2; ++kf) {
        const float* base = &hs_acc[m * SA + kf * 32 + q * 8];
        float4 u0 = *reinterpret_cast<const float4*>(base);
        float4 u1 = *reinterpret_cast<const float4*>(base + 4);
        float u[8] = {u0.x, u0.y, u0.z, u0.w, u1.x, u1.y, u1.z, u1.w};
        split8(u, ah[kf], al[kf]);
    }
    // no barrier: h goes to a separate LDS buffer

    // ---- phase 1: h = relu(A@W1 + b1) -> hs_h (cg split across 4 waves) ----
    __builtin_amdgcn_s_setprio(1);
#pragma unroll
    for (int cgi = 0; cgi < CGH1; ++cgi) {
        const int cg = wk * CGH1 + cgi;
        ffrag c = {0.f, 0.f, 0.f, 0.f};
#pragma unroll
        for (int kf = 0; kf < 2; ++kf) {
            bfrag bh = w1hp[(cg * 2 + kf) * 64 + lane];
            bfrag bl = w1lp[(cg * 2 + kf) * 64 + lane];
            c = __builtin_amdgcn_mfma_f32_16x16x32_bf16(ah[kf], bh, c, 0, 0, 0);
            c = __builtin_amdgcn_mfma_f32_16x16x32_bf16(al[kf], bh, c, 0, 0, 0);
            c = __builtin_amdgcn_mfma_f32_16x16x32_bf16(ah[kf], bl, c, 0, 0, 0);
        }
        float bias = b1[cg * 16 + m];
#pragma unroll
        for (int r = 0; r < 4; ++r) {
            float hv = fmaxf(c[r] + bias, 0.f);
            hs_h[(q * 4 + r) * SH1 + cg * 16 + m] = hv;   // row=node, col=h-col
        }
    }
    __builtin_amdgcn_s_setprio(0);
    __syncthreads();   // barrier 2: h complete

    // ---- h -> A frags (hi/lo), full K per wave ----
    bfrag gh[KF2], gl[KF2];
#pragma unroll
    for (int kf = 0; kf < KF2; ++kf) {
        const float* base = &hs_h[m * SH1 + kf * 32 + q * 8];
        float4 u0 = *reinterpret_cast<const float4*>(base);
        float4 u1 = *reinterpret_cast<const float4*>(base + 4);
        float u[8] = {u0.x, u0.y, u0.z, u0.w, u1.x, u1.y, u1.z, u1.w};
        split8(u, gh[kf], gl[kf]);
    }

    // ---- phase 2: out = h@W2 + b2 (one output cg per wave) ----
    {
        const int cg = wk;
        ffrag c = {0.f, 0.f, 0.f, 0.f};
        __builtin_amdgcn_s_setprio(1);
#pragma unroll
        for (int kf = 0; kf < KF2; ++kf) {
            bfrag bh = w2hp[(cg * KF2 + kf) * 64 + lane];
            bfrag bl = w2lp[(cg * KF2 + kf) * 64 + lane];
            c = __builtin_amdgcn_mfma_f32_16x16x32_bf16(gh[kf], bh, c, 0, 0, 0);
            c = __builtin_amdgcn_mfma_f32_16x16x32_bf16(gl[kf], bh, c, 0, 0, 0);
            c = __builtin_amdgcn_mfma_f32_16x16x32_bf16(gh[kf], bl, c, 0, 0, 0);
        }
        __builtin_amdgcn_s_setprio(0);
        float bias = b2[cg * 16 + m];
#pragma unroll
        for (int r = 0; r < 4; ++r) {
            int nd = tnode0 + q * 4 + r;
            float v = c[r] + bias;
            if (RELU_OUT) v = fmaxf(v, 0.f);
            if (OUT_BF16)
                ((unsigned short*)outv)[(size_t)nd * FEAT + cg * 16 + m] = f2bf_rne(v);
            else
                ((float*)outv)[(size_t)nd * FEAT + cg * 16 + m] = v;
        }
    }
}

// ---------------------------------------------------------------------------
extern "C" void kernel_launch(void* const* d_in, const int* in_sizes, int n_in,
                              void* d_out, int out_size, void* d_ws, size_t ws_size,
                              hipStream_t stream) {
    const float* x   = (const float*)d_in[0];
    const int*   ei  = (const int*)  d_in[1];
    const float* ew  = (const float*)d_in[2];
    const float* w11 = (const float*)d_in[3];
    const float* b11 = (const float*)d_in[4];
    const float* w12 = (const float*)d_in[5];
    const float* b12 = (const float*)d_in[6];
    const float* w21 = (const float*)d_in[7];
    const float* b21 = (const float*)d_in[8];
    const float* w22 = (const float*)d_in[9];
    const float* b22 = (const float*)d_in[10];
    const float* w31 = (const float*)d_in[11];
    const float* b31 = (const float*)d_in[12];
    const float* w32 = (const float*)d_in[13];
    const float* b32 = (const float*)d_in[14];

    const int N = in_sizes[0] / FEAT;   // 100000
    const int E = in_sizes[2];          // 1000000
    const int* srci = ei;
    const int* dsti = ei + E;
    const int NBINS = (N + BINW - 1) >> BSH;   // 782

    // ---- workspace layout ----
    unsigned short* xb0 = (unsigned short*)d_ws;             // [N*64] bf16
    unsigned short* xb1 = xb0 + (size_t)N * FEAT;            // [N*64] bf16
    int2*  hdr      = (int2*)(xb1 + (size_t)N * FEAT);       // [N] (obeg, ocnt)
    int2*  first16  = hdr + N;                               // [N*16]
    int*   counts   = (int*)(first16 + (size_t)N * 16);      // [NBINS*NBLK]
    int*   bintotal = counts + NBINS * NBLK;                 // [NBINS]
    int*   binstart = bintotal + NBINS;                      // [NBINS+1]
    size_t a16 = ((size_t)(binstart + NBINS + 1) + 15) & ~(size_t)15;
    int2*  binbuf   = (int2*)a16;                            // [E] (key, w)
    int2*  ovfbuf   = binbuf + E;                            // [NBINS*OVFSLACK]
    size_t pk = (size_t)(ovfbuf + (size_t)NBINS * OVFSLACK);
    unsigned short* p11h = (unsigned short*)pk;              // 4096 each for 64x64
    unsigned short* p11l = p11h + 4096;
    unsigned short* p12h = p11l + 4096;
    unsigned short* p12l = p12h + 4096;
    unsigned short* p21h = p12l + 4096;                      // 8192 for 64x128
    unsigned short* p21l = p21h + 8192;
    unsigned short* p22h = p21l + 8192;                      // 8192 for 128x64
    unsigned short* p22l = p22h + 8192;
    unsigned short* p31h = p22l + 8192;
    unsigned short* p31l = p31h + 4096;
    unsigned short* p32h = p31l + 4096;
    unsigned short* p32l = p32h + 4096;
    float* outF = (float*)d_out;                             // [N*64]

    const int n4   = N * 16;
    const int gCvt = (n4 + 255) / 256;
    const int gMlp = (N + 15) / 16;            // 6250 blocks, 25000 waves
    const int gPre = gCvt + NBLK + 128;

    // ---- pre: cvt + histogram + weight pack (one launch) ----
    k_pre<<<gPre, 256, 0, stream>>>((const float4*)x, (ushort4*)xb0, n4, gCvt,
                                    dsti, counts, E, NBINS,
                                    w11, w12, w21, w22, w31, w32,
                                    p11h, p11l, p12h, p12l, p21h, p21l,
                                    p22h, p22l, p31h, p31l, p32h, p32l);
    // ---- CSR build (first16 + overflow) ----
    k_scanA2 <<<NBINS, 256, 0, stream>>>(counts, bintotal, NBINS);
    k_place2 <<<NBLK,  256, 0, stream>>>(srci, dsti, ew, counts, bintotal,
                                         binstart, binbuf, E, NBINS);
    k_binsort<<<NBINS, 256, 0, stream>>>(binbuf, binstart, hdr, first16,
                                         ovfbuf, N);

    // ---- fused layers (double-buffered activations) ----
    k_fused<64,  true,  true ><<<gMlp, 256, 0, stream>>>(xb0, xb1, hdr, first16, ovfbuf,
                                                         p11h, p11l, b11, p12h, p12l, b12, N);
    k_fused<128, true,  true ><<<gMlp, 256, 0, stream>>>(xb1, xb0, hdr, first16, ovfbuf,
                                                         p21h, p21l, b21, p22h, p22l, b22, N);
    k_fused<64,  false, false><<<gMlp, 256, 0, stream>>>(xb0, outF, hdr, first16, ovfbuf,
                                                         p31h, p31l, b31, p32h, p32l, b32, N);
}